// Round 7
// baseline (143.774 us; speedup 1.0000x reference)
//
#include <hip/hip_runtime.h>
#include <hip/hip_fp16.h>

typedef _Float16 half8 __attribute__((ext_vector_type(8)));
typedef _Float16 half4 __attribute__((ext_vector_type(4)));
typedef float floatx4 __attribute__((ext_vector_type(4)));

#define T_SEQ 2048
#define NB    8

// ---------------------------------------------------------------------------
// Kernel 0: prep — WqT f16 [64][768]
// ---------------------------------------------------------------------------
__global__ __launch_bounds__(256) void prep_kernel(
    const float* __restrict__ Wq, _Float16* __restrict__ WqT)
{
  const int h = blockIdx.x, tid = threadIdx.x;
  for (int k = tid; k < 768; k += 256)
    WqT[h * 768 + k] = (_Float16)Wq[k * 64 + h];
}

// ---------------------------------------------------------------------------
// Kernel 1: q = x @ Wq. Wave-autonomous streaming: 1024 blocks x 64 threads,
// one wave owns one 16-row tile. A-frags direct from global x (16 x 128-B
// segments per chunk, all bytes used), explicit 2-group register double
// buffer; B re-read from L2 per chunk. Zero LDS, zero barriers -> no
// vmcnt(0) drain; per-wave MLP keeps HBM saturated.
// Emits per-row softmax offset Ct = (|q|^2/8)*log2e + bias0*log2e + 8.
// ---------------------------------------------------------------------------
__global__ __launch_bounds__(64, 2) void qproj_kernel(
    const float* __restrict__ x, const _Float16* __restrict__ WqT,
    const float* __restrict__ rel,
    _Float16* __restrict__ q16, _Float16* __restrict__ q16T,
    float* __restrict__ Ct)
{
  const int lane = threadIdx.x;
  const int n = lane & 15, quad = lane >> 4;
  const int r0 = blockIdx.x * 16;

  const float*    xp = x   + (size_t)(r0 + n) * 768 + quad * 8;
  const _Float16* wp = WqT + (size_t)n * 768 + quad * 8;

  // A double-buffer: 2 groups x 4 chunks x 32 floats/lane-pair
  float4 A[2][8];
  #pragma unroll
  for (int i = 0; i < 4; ++i) {
    A[0][2 * i]     = *(const float4*)(xp + 32 * i);
    A[0][2 * i + 1] = *(const float4*)(xp + 32 * i + 4);
  }

  floatx4 acc[4];
  #pragma unroll
  for (int s = 0; s < 4; ++s) acc[s] = (floatx4){0.f, 0.f, 0.f, 0.f};

  #pragma unroll
  for (int g = 0; g < 6; ++g) {
    const int cur = g & 1, nxt = cur ^ 1;
    if (g < 5) {
      #pragma unroll
      for (int i = 0; i < 4; ++i) {
        A[nxt][2 * i]     = *(const float4*)(xp + 128 * (g + 1) + 32 * i);
        A[nxt][2 * i + 1] = *(const float4*)(xp + 128 * (g + 1) + 32 * i + 4);
      }
    }
    #pragma unroll
    for (int i = 0; i < 4; ++i) {
      const int kc = 128 * g + 32 * i;
      half8 b0 = *(const half8*)(wp + kc);
      half8 b1 = *(const half8*)(wp + 16 * 768 + kc);
      half8 b2 = *(const half8*)(wp + 32 * 768 + kc);
      half8 b3 = *(const half8*)(wp + 48 * 768 + kc);
      half8 a;
      a[0] = (_Float16)A[cur][2 * i].x; a[1] = (_Float16)A[cur][2 * i].y;
      a[2] = (_Float16)A[cur][2 * i].z; a[3] = (_Float16)A[cur][2 * i].w;
      a[4] = (_Float16)A[cur][2 * i + 1].x; a[5] = (_Float16)A[cur][2 * i + 1].y;
      a[6] = (_Float16)A[cur][2 * i + 1].z; a[7] = (_Float16)A[cur][2 * i + 1].w;
      acc[0] = __builtin_amdgcn_mfma_f32_16x16x32_f16(a, b0, acc[0], 0, 0, 0);
      acc[1] = __builtin_amdgcn_mfma_f32_16x16x32_f16(a, b1, acc[1], 0, 0, 0);
      acc[2] = __builtin_amdgcn_mfma_f32_16x16x32_f16(a, b2, acc[2], 0, 0, 0);
      acc[3] = __builtin_amdgcn_mfma_f32_16x16x32_f16(a, b3, acc[3], 0, 0, 0);
    }
  }

  // epilogue: all in registers. C layout: row = quad*4 + r (t), col = sub*16+n (h)
  const float b0v = rel[2047] * 1.44269504f;
  float ss[4] = {0.f, 0.f, 0.f, 0.f};
  const int bb = r0 >> 11, tt = (r0 & 2047) + quad * 4;
  #pragma unroll
  for (int sub = 0; sub < 4; ++sub) {
    half4 hv;
    #pragma unroll
    for (int r = 0; r < 4; ++r) {
      float v = acc[sub][r];
      q16[(size_t)(r0 + quad * 4 + r) * 64 + sub * 16 + n] = (_Float16)v;
      hv[r] = (_Float16)v;
      ss[r] += v * v;
    }
    *(half4*)(q16T + (size_t)(bb * 64 + sub * 16 + n) * T_SEQ + tt) = hv;
  }
  #pragma unroll
  for (int off = 1; off < 16; off <<= 1) {
    #pragma unroll
    for (int r = 0; r < 4; ++r) ss[r] += __shfl_xor(ss[r], off);
  }
  if (n == 0) {
    #pragma unroll
    for (int r = 0; r < 4; ++r)
      Ct[r0 + quad * 4 + r] = ss[r] * 0.18033688f + b0v + 8.0f;
  }
}

// ---------------------------------------------------------------------------
// Kernel 2: attention, fixed-offset softmax. 512 blocks x 512 thr (8 waves);
// block = (b, pair p): q-tiles p and 127-p -> identical work per block under
// any dispatch mapping. k-split 8 across waves; 60 KB LDS -> 2 blocks/CU ->
// 16 waves/CU; VGPR capped at 128 by __launch_bounds__(512,4).
// ---------------------------------------------------------------------------
__global__ __launch_bounds__(512, 4) void attn_kernel(
    const _Float16* __restrict__ q16, const _Float16* __restrict__ q16T,
    const float* __restrict__ rel, const float* __restrict__ Ct,
    float* __restrict__ out)
{
  __shared__ __align__(16) _Float16 Pbuf[8 * 16 * 72];  // 18432 B
  __shared__ float Obuf[8 * 16 * 65];                   // 33280 B
  __shared__ float Lbuf[8 * 16];                        // 512 B
  __shared__ float biasL[2080];                         // 8320 B

  const int bi = blockIdx.x;
  const int b  = bi & 7;
  const int p  = bi >> 3;               // [0,64)

  const int tid  = threadIdx.x;
  const int w    = tid >> 6;
  const int lane = tid & 63;
  const int n    = lane & 15, quad = lane >> 4;

  _Float16* Pw = Pbuf + w * 1152;
  const float ksc = 0.125f * 1.44269504f;
  const _Float16* vbase = q16T + (size_t)(b * 64 + n) * T_SEQ + quad * 8;
  const half8 ones = {(_Float16)1, (_Float16)1, (_Float16)1, (_Float16)1,
                      (_Float16)1, (_Float16)1, (_Float16)1, (_Float16)1};

  #pragma unroll 1
  for (int ht = 0; ht < 2; ++ht) {
    const int qi = ht ? (127 - p) : p;
    const int t0 = qi * 16;
    const int kfull = t0 >> 6;          // tiles [0,kfull) unmasked; kfull = diag

    __syncthreads();                    // previous combine done -> reuse LDS

    // stage bias slice (*log2e) straight from rel
    {
      const int lo = 2032 - t0, cnt = t0 + 31;
      for (int i = tid; i < cnt; i += 512) biasL[i] = rel[lo + i] * 1.44269504f;
    }

    half8 aq0, aq1;
    {
      const _Float16* qrow = q16 + (size_t)(b * T_SEQ + t0 + n) * 64 + quad * 8;
      aq0 = *(const half8*)qrow;
      aq1 = *(const half8*)(qrow + 32);
    }
    float ctv[4];
    #pragma unroll
    for (int r = 0; r < 4; ++r)
      ctv[r] = Ct[b * T_SEQ + t0 + 4 * quad + r];

    floatx4 O[4];
    #pragma unroll
    for (int s = 0; s < 4; ++s) O[s] = (floatx4){0.f, 0.f, 0.f, 0.f};
    floatx4 den = (floatx4){0.f, 0.f, 0.f, 0.f};

    __syncthreads();                    // biasL visible

    for (int kt = w; kt <= kfull; kt += 8) {
      const int  s0 = kt * 64;
      const bool dg = (kt == kfull);
      const int  j  = (t0 - s0) >> 4;   // valid when dg

      // K fragments for this tile
      half8 cK[8], cV[8];
      #pragma unroll
      for (int sub = 0; sub < 4; ++sub) {
        const _Float16* kp =
            q16 + (size_t)(b * T_SEQ + s0 + sub * 16 + n) * 64 + quad * 8;
        cK[2 * sub]     = *(const half8*)kp;
        cK[2 * sub + 1] = *(const half8*)(kp + 32);
      }
      #pragma unroll
      for (int sh = 0; sh < 4; ++sh) {
        cV[sh]     = *(const half8*)(vbase + (size_t)(sh * 16) * T_SEQ + s0);
        cV[4 + sh] = *(const half8*)(vbase + (size_t)(sh * 16) * T_SEQ + s0 + 32);
      }

      #pragma unroll
      for (int sub = 0; sub < 4; ++sub) {
        if (dg && sub > j) {
          #pragma unroll
          for (int r = 0; r < 4; ++r)
            Pw[(4 * quad + r) * 72 + sub * 16 + n] = (_Float16)0.f;
          continue;
        }
        floatx4 sc = (floatx4){0.f, 0.f, 0.f, 0.f};
        sc = __builtin_amdgcn_mfma_f32_16x16x32_f16(aq0, cK[2 * sub], sc, 0, 0, 0);
        sc = __builtin_amdgcn_mfma_f32_16x16x32_f16(aq1, cK[2 * sub + 1], sc, 0, 0, 0);
        const int smin = s0 + sub * 16;
        #pragma unroll
        for (int r = 0; r < 4; ++r) {
          float bv = biasL[15 + smin + n - 4 * quad - r];
          float pv = exp2f(fmaf(sc[r], ksc, bv) - ctv[r]);
          if (dg && sub == j && n > 4 * quad + r) pv = 0.f;  // causal diagonal
          Pw[(4 * quad + r) * 72 + sub * 16 + n] = (_Float16)pv;
        }
      }

      #pragma unroll
      for (int ch = 0; ch < 2; ++ch) {
        half8 pf = *(const half8*)(Pw + n * 72 + ch * 32 + quad * 8);
        den = __builtin_amdgcn_mfma_f32_16x16x32_f16(pf, ones, den, 0, 0, 0);
        #pragma unroll
        for (int sh = 0; sh < 4; ++sh)
          O[sh] = __builtin_amdgcn_mfma_f32_16x16x32_f16(pf, cV[ch * 4 + sh],
                                                         O[sh], 0, 0, 0);
      }
    }

    // per-wave partials
    #pragma unroll
    for (int sub = 0; sub < 4; ++sub)
      #pragma unroll
      for (int r = 0; r < 4; ++r)
        Obuf[w * 1040 + (4 * quad + r) * 65 + sub * 16 + n] = O[sub][r];
    if (n == 0) {
      #pragma unroll
      for (int r = 0; r < 4; ++r)
        Lbuf[w * 16 + 4 * quad + r] = den[r];
    }
    __syncthreads();

    // 8-way combine + output (1024 elems over 512 threads)
    #pragma unroll
    for (int k = 0; k < 2; ++k) {
      const int e = tid + k * 512;
      const int row = e >> 6, h = e & 63;
      float num = 0.f, d = 0.f;
      #pragma unroll
      for (int w8 = 0; w8 < 8; ++w8) {
        num += Obuf[w8 * 1040 + row * 65 + h];
        d   += Lbuf[w8 * 16 + row];
      }
      out[(size_t)(b * T_SEQ + t0 + row) * 64 + h] = num / d;
    }
  }
}

// ---------------------------------------------------------------------------
extern "C" void kernel_launch(void* const* d_in, const int* in_sizes, int n_in,
                              void* d_out, int out_size, void* d_ws, size_t ws_size,
                              hipStream_t stream) {
  const float* x   = (const float*)d_in[0];
  const float* Wq  = (const float*)d_in[1];
  const float* rel = (const float*)d_in[2];
  float* out = (float*)d_out;

  _Float16* q16  = (_Float16*)d_ws;                    // [8][2048][64]
  _Float16* q16T = q16  + (size_t)NB * T_SEQ * 64;     // [8][64][2048]
  _Float16* WqT  = q16T + (size_t)NB * T_SEQ * 64;     // [64][768]
  float*    Ct   = (float*)(WqT + 64 * 768);           // [16384]

  prep_kernel <<<64,   256, 0, stream>>>(Wq, WqT);
  qproj_kernel<<<1024,  64, 0, stream>>>(x, WqT, rel, q16, q16T, Ct);
  attn_kernel <<<512,  512, 0, stream>>>(q16, q16T, rel, Ct, out);
}